// Round 1
// 1913.759 us; speedup vs baseline: 1.0307x; 1.0307x over previous
//
#include <hip/hip_runtime.h>
#include <hip/hip_bf16.h>

// B=256, T=2048, I=H=256, O=16. fp32 in/out. xp kept f16 as [b][t][n].

typedef _Float16 f16;
typedef _Float16 h8_t __attribute__((ext_vector_type(8)));
typedef _Float16 h2_t __attribute__((ext_vector_type(2)));
typedef float    f4_t __attribute__((ext_vector_type(4)));

__device__ __forceinline__ float fdot2u(unsigned w, unsigned h, float c) {
  return __builtin_amdgcn_fdot2(__builtin_bit_cast(h2_t, w),
                                __builtin_bit_cast(h2_t, h), c, false);
}
__device__ __forceinline__ unsigned pkrtz(float a, float b) {
  return __builtin_bit_cast(unsigned, __builtin_amdgcn_cvt_pkrtz(a, b));
}

// ---------------------------------------------------------------------------
// prep: Wfrag = W_ih in exact MFMA B-fragment order (coalesced preload),
//       Wc2   = W_hh packed f16-pairs, OUTPUT-MAJOR per-lane granules:
// Wc2[g*256 + j] (g=0..31, j=0..255): uint4 of 4 k-pairs for output column j,
//   component c packs (Whh[8g+2c][j], Whh[8g+2c+1][j]).  Lane j of the rnn
//   kernel owns output j with the full K=256 in 32 uint4 (128 VGPRs).
// ---------------------------------------------------------------------------
__global__ __launch_bounds__(256) void prep_kernel(const float* __restrict__ Wih,
                                                   const float* __restrict__ Whh,
                                                   uint4* __restrict__ Wfrag,
                                                   uint4* __restrict__ Wc2) {
  int idx = blockIdx.x * 256 + threadIdx.x;   // 0..16383
  int e = idx & 8191;
  int gi = e >> 8;          // 0..31
  int lg = e & 255;         // w*64+l
  int w = lg >> 6, l = lg & 63;
  unsigned r[4];
  if (idx < 8192) {
    int nt = gi >> 3, ks = gi & 7;
    int n = w * 64 + nt * 16 + (l & 15);
    int k0 = ks * 32 + (l >> 4) * 8;
#pragma unroll
    for (int c = 0; c < 4; ++c)
      r[c] = pkrtz(Wih[(k0 + 2 * c) * 256 + n], Wih[(k0 + 2 * c + 1) * 256 + n]);
    Wfrag[gi * 256 + lg] = make_uint4(r[0], r[1], r[2], r[3]);
  } else {
    int j = lg;                               // output column
    int kb = gi * 8;                          // k-base of granule
#pragma unroll
    for (int c = 0; c < 4; ++c)
      r[c] = pkrtz(Whh[(kb + 2 * c) * 256 + j], Whh[(kb + 2 * c + 1) * 256 + j]);
    Wc2[gi * 256 + lg] = make_uint4(r[0], r[1], r[2], r[3]);
  }
}

// ---------------------------------------------------------------------------
// GEMM: block = (batch b, 64-step t-tile). x tile is 64KB CONTIGUOUS fp32:
// coalesced load -> f16 -> padded LDS. W frags persistent in VGPRs (coalesced
// preload from Wfrag). 128 MFMA/wave. xp[b][t][n] f16 out.
// ---------------------------------------------------------------------------
__global__ __launch_bounds__(256, 2) void gemm_kernel(const float* __restrict__ x,
                                                      const uint4* __restrict__ Wfrag,
                                                      f16* __restrict__ xp,
                                                      int t0, int CT, int tpc) {
  __shared__ f16 As[64][264];                 // +8 f16 pad per row
  int tid = threadIdx.x;
  int wave = tid >> 6, l = tid & 63, l15 = l & 15, q = l >> 4;

  uint4 bf[4][8];
#pragma unroll
  for (int nt = 0; nt < 4; ++nt)
#pragma unroll
    for (int ks = 0; ks < 8; ++ks)
      bf[nt][ks] = Wfrag[(nt * 8 + ks) * 256 + tid];

  int blk = blockIdx.x;
  int b = blk / tpc, tt = blk - b * tpc;
  int tl0 = tt * 64;

  const uint4* xsrc = (const uint4*)(x + ((size_t)b * 2048 + t0 + tl0) * 256);
#pragma unroll
  for (int i = 0; i < 16; ++i) {              // 64KB tile: 16 uint4/thread
    int fi = i * 256 + tid;
    float4 f = __builtin_bit_cast(float4, xsrc[fi]);
    int row = fi >> 6;                        // t-row 0..63
    int k = (fi & 63) * 4;
    uint2 pv; pv.x = pkrtz(f.x, f.y); pv.y = pkrtz(f.z, f.w);
    *(uint2*)&As[row][k] = pv;
  }
  __syncthreads();

  f4_t acc[4][4];
#pragma unroll
  for (int mt = 0; mt < 4; ++mt)
#pragma unroll
    for (int nt = 0; nt < 4; ++nt) acc[mt][nt] = (f4_t){0.f, 0.f, 0.f, 0.f};

  for (int mt = 0; mt < 4; ++mt) {
    uint4 af[8];
#pragma unroll
    for (int ks = 0; ks < 8; ++ks)
      af[ks] = *(const uint4*)&As[mt * 16 + l15][ks * 32 + q * 8];
#pragma unroll
    for (int ks = 0; ks < 8; ++ks) {
      h8_t a = __builtin_bit_cast(h8_t, af[ks]);
#pragma unroll
      for (int nt = 0; nt < 4; ++nt)
        acc[mt][nt] = __builtin_amdgcn_mfma_f32_16x16x32_f16(
            a, __builtin_bit_cast(h8_t, bf[nt][ks]), acc[mt][nt], 0, 0, 0);
    }
  }

  f16* xpo = xp + (size_t)b * CT * 256;       // xp[b][tl][n]
#pragma unroll
  for (int mt = 0; mt < 4; ++mt)
#pragma unroll
    for (int nt = 0; nt < 4; ++nt) {
      int n = wave * 64 + nt * 16 + l15;
#pragma unroll
      for (int r = 0; r < 4; ++r)
        xpo[(size_t)(tl0 + mt * 16 + q * 4 + r) * 256 + n] = (f16)acc[mt][nt][r];
    }
}

// ---------------------------------------------------------------------------
// RNN: 256 blocks (1 batch/CU) x 256 threads. OUTPUT-MAJOR split: lane tid
// owns output j=tid with full K=256 in 128 VGPRs of f16-pairs. Per step:
// 32 broadcast ds_read_b128 of h + 128 fdot2 + in-lane tanh + 1 f16 h-write.
// No cross-wave partial reduce; ONE barrier/step (double-buffered h; a wave's
// reads drain at its own lgkmcnt(0) before it arrives at the barrier, so the
// next step's overwrite of the other buffer cannot race).
// Raw s_barrier + lgkmcnt-only wait: vmcnt never drains in the loop, so the
// 4-step-deep xp prefetch (rotating regs n0..n3, consumed 3 steps after
// issue ~ 1500 cyc > 900 cyc HBM latency) stays in flight across barriers.
// __launch_bounds__(256,1): 512-VGPR budget keeps 128-reg weight array live.
// ---------------------------------------------------------------------------
__global__ __launch_bounds__(256, 1) void rnn_kernel(const f16* __restrict__ xp,
                                                     const uint4* __restrict__ Wc2,
                                                     const float* __restrict__ b_h,
                                                     const float* __restrict__ fc_w,
                                                     const float* __restrict__ fc_b,
                                                     float* __restrict__ hstate,
                                                     float* __restrict__ out,
                                                     int t0, int CT) {
  __shared__ __align__(16) f16 hbuf[2][256];
  __shared__ float hf[256];
  __shared__ float prt2[16][16];

  int b = blockIdx.x, tid = threadIdx.x;

  uint4 wv[32];                                // 128 VGPRs: W_hh column tid
#pragma unroll
  for (int g = 0; g < 32; ++g) wv[g] = Wc2[g * 256 + tid];

  float hcur = (t0 == 0) ? 0.0f : hstate[b * 256 + tid];
  hbuf[0][tid] = (f16)hcur;
  float bhv = b_h[tid];

  const f16* xpb = xp + (size_t)b * CT * 256 + tid;
  float xv = (float)xpb[0] + bhv;              // xv carries +b_h folded in
  f16 n0, n1, n2, n3;                          // rotating 4-deep prefetch
  n1 = xpb[256];
  n2 = xpb[512];
  n3 = xpb[768];
  __syncthreads();

#define RNN_STEP(T, PAR, NLOAD, NUSE)                                       \
  {                                                                         \
    int pf = (T) + 4;                                                       \
    if (pf > CT - 1) pf = CT - 1;                                           \
    NLOAD = xpb[(size_t)pf * 256];                                          \
    const uint4* hb = (const uint4*)&hbuf[PAR][0];                          \
    float a0 = 0.f, a1 = 0.f, a2 = 0.f, a3 = 0.f;                           \
    float a4 = 0.f, a5 = 0.f, a6 = 0.f, a7 = 0.f;                           \
    _Pragma("unroll") for (int g8 = 0; g8 < 4; ++g8) {                      \
      uint4 hh[8];                                                          \
      _Pragma("unroll") for (int u = 0; u < 8; ++u) hh[u] = hb[g8 * 8 + u]; \
      _Pragma("unroll") for (int u = 0; u < 8; u += 2) {                    \
        uint4 w0 = wv[g8 * 8 + u], w1 = wv[g8 * 8 + u + 1];                 \
        a0 = fdot2u(w0.x, hh[u].x, a0);                                     \
        a1 = fdot2u(w0.y, hh[u].y, a1);                                     \
        a2 = fdot2u(w0.z, hh[u].z, a2);                                     \
        a3 = fdot2u(w0.w, hh[u].w, a3);                                     \
        a4 = fdot2u(w1.x, hh[u + 1].x, a4);                                 \
        a5 = fdot2u(w1.y, hh[u + 1].y, a5);                                 \
        a6 = fdot2u(w1.z, hh[u + 1].z, a6);                                 \
        a7 = fdot2u(w1.w, hh[u + 1].w, a7);                                 \
      }                                                                     \
    }                                                                       \
    float z = ((a0 + a4) + (a1 + a5)) + (((a2 + a6) + (a3 + a7)) + xv);     \
    float e = __expf(2.0f * z);                                             \
    hcur = 1.0f - 2.0f * __builtin_amdgcn_rcpf(e + 1.0f);                   \
    hbuf[(PAR) ^ 1][tid] = (f16)hcur;                                       \
    xv = (float)(NUSE) + bhv;                                               \
    asm volatile("s_waitcnt lgkmcnt(0)" ::: "memory");                      \
    __builtin_amdgcn_s_barrier();                                           \
    __builtin_amdgcn_sched_barrier(0);                                      \
  }

  for (int tt = 0; tt < CT; tt += 4) {
    RNN_STEP(tt + 0, 0, n0, n1)
    RNN_STEP(tt + 1, 1, n1, n2)
    RNN_STEP(tt + 2, 0, n2, n3)
    RNN_STEP(tt + 3, 1, n3, n0)
  }
#undef RNN_STEP

  hstate[b * 256 + tid] = hcur;

  if (t0 + CT == 2048) {                       // fused fp32 classifier head
    hf[tid] = hcur;
    __syncthreads();
    int o = tid >> 4, s2 = tid & 15;
    const float* fw = fc_w + o * 256 + s2 * 16;
    float p = 0.f;
#pragma unroll
    for (int i = 0; i < 16; ++i) p += hf[s2 * 16 + i] * fw[i];
    prt2[o][s2] = p;
    __syncthreads();
    if (tid < 16) {
      float r = fc_b[tid];
#pragma unroll
      for (int s3 = 0; s3 < 16; ++s3) r += prt2[tid][s3];
      out[b * 16 + tid] = r;
    }
  }
}

// ---------------------------------------------------------------------------
extern "C" void kernel_launch(void* const* d_in, const int* in_sizes, int n_in,
                              void* d_out, int out_size, void* d_ws, size_t ws_size,
                              hipStream_t stream) {
  const float* x   = (const float*)d_in[0];
  const float* Wih = (const float*)d_in[1];
  const float* Whh = (const float*)d_in[2];
  const float* bh  = (const float*)d_in[3];
  const float* fcw = (const float*)d_in[4];
  const float* fcb = (const float*)d_in[5];
  float* out = (float*)d_out;

  char* ws = (char*)d_ws;
  uint4* Wfrag  = (uint4*)ws;                        // 128 KB
  uint4* Wc2    = (uint4*)(ws + (128 << 10));        // 128 KB
  float* hstate = (float*)(ws + (256 << 10));        // 256 KB
  f16*   xpb    = (f16*)(ws + (512 << 10));          // chunk buffer

  size_t avail = (ws_size > (size_t)(512 << 10)) ? ws_size - (size_t)(512 << 10) : 0;
  int CT = 2048;
  while (CT > 64 && (size_t)CT * 131072 > avail) CT >>= 1;
  int tpc = CT >> 6;                                 // 64-step tiles per chunk

  prep_kernel<<<64, 256, 0, stream>>>(Wih, Whh, Wfrag, Wc2);
  for (int t0 = 0; t0 < 2048; t0 += CT) {
    gemm_kernel<<<256 * tpc, 256, 0, stream>>>(x, Wfrag, xpb, t0, CT, tpc);
    rnn_kernel<<<256, 256, 0, stream>>>(xpb, Wc2, bh, fcw, fcb, hstate, out, t0, CT);
  }
}

// Round 2
// 1910.718 us; speedup vs baseline: 1.0324x; 1.0016x over previous
//
#include <hip/hip_runtime.h>
#include <hip/hip_bf16.h>

// B=256, T=2048, I=H=256, O=16. fp32 in/out. xp kept f16 as [b][t][n].

typedef _Float16 f16;
typedef _Float16 h8_t __attribute__((ext_vector_type(8)));
typedef _Float16 h2_t __attribute__((ext_vector_type(2)));
typedef float    f4_t __attribute__((ext_vector_type(4)));

__device__ __forceinline__ float fdot2u(unsigned w, unsigned h, float c) {
  return __builtin_amdgcn_fdot2(__builtin_bit_cast(h2_t, w),
                                __builtin_bit_cast(h2_t, h), c, false);
}
__device__ __forceinline__ unsigned pkrtz(float a, float b) {
  return __builtin_bit_cast(unsigned, __builtin_amdgcn_cvt_pkrtz(a, b));
}

// ---------------------------------------------------------------------------
// prep: Wfrag = W_ih in exact MFMA B-fragment order (coalesced preload),
//       Wc2   = W_hh packed f16-pairs, OUTPUT-MAJOR per-lane granules:
// Wc2[g*256 + j] (g=0..31, j=0..255): uint4 of 4 k-pairs for output column j,
//   component c packs (Whh[8g+2c][j], Whh[8g+2c+1][j]).  Lane j of the rnn
//   kernel owns output j with the full K=256 in 32 uint4 (128 VGPRs).
// ---------------------------------------------------------------------------
__global__ __launch_bounds__(256) void prep_kernel(const float* __restrict__ Wih,
                                                   const float* __restrict__ Whh,
                                                   uint4* __restrict__ Wfrag,
                                                   uint4* __restrict__ Wc2) {
  int idx = blockIdx.x * 256 + threadIdx.x;   // 0..16383
  int e = idx & 8191;
  int gi = e >> 8;          // 0..31
  int lg = e & 255;         // w*64+l
  int w = lg >> 6, l = lg & 63;
  unsigned r[4];
  if (idx < 8192) {
    int nt = gi >> 3, ks = gi & 7;
    int n = w * 64 + nt * 16 + (l & 15);
    int k0 = ks * 32 + (l >> 4) * 8;
#pragma unroll
    for (int c = 0; c < 4; ++c)
      r[c] = pkrtz(Wih[(k0 + 2 * c) * 256 + n], Wih[(k0 + 2 * c + 1) * 256 + n]);
    Wfrag[gi * 256 + lg] = make_uint4(r[0], r[1], r[2], r[3]);
  } else {
    int j = lg;                               // output column
    int kb = gi * 8;                          // k-base of granule
#pragma unroll
    for (int c = 0; c < 4; ++c)
      r[c] = pkrtz(Whh[(kb + 2 * c) * 256 + j], Whh[(kb + 2 * c + 1) * 256 + j]);
    Wc2[gi * 256 + lg] = make_uint4(r[0], r[1], r[2], r[3]);
  }
}

// ---------------------------------------------------------------------------
// GEMM: block = (batch b, 64-step t-tile). x tile is 64KB CONTIGUOUS fp32:
// coalesced load -> f16 -> padded LDS. W frags persistent in VGPRs (coalesced
// preload from Wfrag). 128 MFMA/wave. xp[b][t][n] f16 out.
// ---------------------------------------------------------------------------
__global__ __launch_bounds__(256, 2) void gemm_kernel(const float* __restrict__ x,
                                                      const uint4* __restrict__ Wfrag,
                                                      f16* __restrict__ xp,
                                                      int t0, int CT, int tpc) {
  __shared__ f16 As[64][264];                 // +8 f16 pad per row
  int tid = threadIdx.x;
  int wave = tid >> 6, l = tid & 63, l15 = l & 15, q = l >> 4;

  uint4 bf[4][8];
#pragma unroll
  for (int nt = 0; nt < 4; ++nt)
#pragma unroll
    for (int ks = 0; ks < 8; ++ks)
      bf[nt][ks] = Wfrag[(nt * 8 + ks) * 256 + tid];

  int blk = blockIdx.x;
  int b = blk / tpc, tt = blk - b * tpc;
  int tl0 = tt * 64;

  const uint4* xsrc = (const uint4*)(x + ((size_t)b * 2048 + t0 + tl0) * 256);
#pragma unroll
  for (int i = 0; i < 16; ++i) {              // 64KB tile: 16 uint4/thread
    int fi = i * 256 + tid;
    float4 f = __builtin_bit_cast(float4, xsrc[fi]);
    int row = fi >> 6;                        // t-row 0..63
    int k = (fi & 63) * 4;
    uint2 pv; pv.x = pkrtz(f.x, f.y); pv.y = pkrtz(f.z, f.w);
    *(uint2*)&As[row][k] = pv;
  }
  __syncthreads();

  f4_t acc[4][4];
#pragma unroll
  for (int mt = 0; mt < 4; ++mt)
#pragma unroll
    for (int nt = 0; nt < 4; ++nt) acc[mt][nt] = (f4_t){0.f, 0.f, 0.f, 0.f};

  for (int mt = 0; mt < 4; ++mt) {
    uint4 af[8];
#pragma unroll
    for (int ks = 0; ks < 8; ++ks)
      af[ks] = *(const uint4*)&As[mt * 16 + l15][ks * 32 + q * 8];
#pragma unroll
    for (int ks = 0; ks < 8; ++ks) {
      h8_t a = __builtin_bit_cast(h8_t, af[ks]);
#pragma unroll
      for (int nt = 0; nt < 4; ++nt)
        acc[mt][nt] = __builtin_amdgcn_mfma_f32_16x16x32_f16(
            a, __builtin_bit_cast(h8_t, bf[nt][ks]), acc[mt][nt], 0, 0, 0);
    }
  }

  f16* xpo = xp + (size_t)b * CT * 256;       // xp[b][tl][n]
#pragma unroll
  for (int mt = 0; mt < 4; ++mt)
#pragma unroll
    for (int nt = 0; nt < 4; ++nt) {
      int n = wave * 64 + nt * 16 + l15;
#pragma unroll
      for (int r = 0; r < 4; ++r)
        xpo[(size_t)(tl0 + mt * 16 + q * 4 + r) * 256 + n] = (f16)acc[mt][nt][r];
    }
}

// ---------------------------------------------------------------------------
// RNN: 256 blocks (1 batch/CU) x 256 threads. OUTPUT-MAJOR split: lane tid
// owns output j=tid with full K=256 in 128 VGPRs of f16-pairs.
//
// CRITICAL: the weight loads from Wc2 are invariant-memory loads and thus
// REMATERIALIZABLE — without the asm register ties below, the register
// allocator re-issues all 32 buffer_load_dwordx4 every timestep (observed:
// VGPR_Count=88 < 128 needed; ~67 GB of L1/L2 weight re-reads per dispatch,
// which was the real bottleneck of rounds 0-1). The `asm ("" : "+v")` tie
// makes each dword an opaque asm output, forcing true VGPR residency.
//
// Per step: 32 broadcast ds_read_b128 of h + 128 fdot2 + in-lane tanh +
// 1 f16 h-write, ONE barrier (double-buffered h; a wave's reads drain at its
// own lgkmcnt(0) before it arrives at the barrier). vmcnt never drains in
// the loop, so the 4-step-deep xp prefetch stays in flight across barriers.
// ---------------------------------------------------------------------------
__global__ __launch_bounds__(256, 1) void rnn_kernel(const f16* __restrict__ xp,
                                                     const uint4* __restrict__ Wc2,
                                                     const float* __restrict__ b_h,
                                                     const float* __restrict__ fc_w,
                                                     const float* __restrict__ fc_b,
                                                     float* __restrict__ hstate,
                                                     float* __restrict__ out,
                                                     int t0, int CT) {
  __shared__ __align__(16) f16 hbuf[2][256];
  __shared__ float hf[256];
  __shared__ float prt2[16][16];

  int b = blockIdx.x, tid = threadIdx.x;

  unsigned wvs[128];                           // 128 VGPRs: W_hh column tid
#pragma unroll
  for (int g = 0; g < 32; ++g) {
    uint4 t = Wc2[g * 256 + tid];
    wvs[4 * g + 0] = t.x;
    wvs[4 * g + 1] = t.y;
    wvs[4 * g + 2] = t.z;
    wvs[4 * g + 3] = t.w;
  }
#pragma unroll
  for (int i = 0; i < 128; ++i)
    asm volatile("" : "+v"(wvs[i]));           // pin: not rematerializable

  float hcur = (t0 == 0) ? 0.0f : hstate[b * 256 + tid];
  hbuf[0][tid] = (f16)hcur;
  float bhv = b_h[tid];

  const f16* xpb = xp + (size_t)b * CT * 256 + tid;
  float xv = (float)xpb[0] + bhv;              // xv carries +b_h folded in
  f16 n0, n1, n2, n3;                          // rotating 4-deep prefetch
  n1 = xpb[256];
  n2 = xpb[512];
  n3 = xpb[768];
  __syncthreads();

#define RNN_STEP(T, PAR, NLOAD, NUSE)                                       \
  {                                                                         \
    int pf = (T) + 4;                                                       \
    if (pf > CT - 1) pf = CT - 1;                                           \
    NLOAD = xpb[(size_t)pf * 256];                                          \
    const uint4* hb = (const uint4*)&hbuf[PAR][0];                          \
    float a0 = 0.f, a1 = 0.f, a2 = 0.f, a3 = 0.f;                           \
    float a4 = 0.f, a5 = 0.f, a6 = 0.f, a7 = 0.f;                           \
    _Pragma("unroll") for (int g8 = 0; g8 < 4; ++g8) {                      \
      uint4 hh[8];                                                          \
      _Pragma("unroll") for (int u = 0; u < 8; ++u) hh[u] = hb[g8 * 8 + u]; \
      _Pragma("unroll") for (int u = 0; u < 8; u += 2) {                    \
        int i0 = (g8 * 8 + u) * 4, i1 = (g8 * 8 + u + 1) * 4;               \
        a0 = fdot2u(wvs[i0 + 0], hh[u].x, a0);                              \
        a1 = fdot2u(wvs[i0 + 1], hh[u].y, a1);                              \
        a2 = fdot2u(wvs[i0 + 2], hh[u].z, a2);                              \
        a3 = fdot2u(wvs[i0 + 3], hh[u].w, a3);                              \
        a4 = fdot2u(wvs[i1 + 0], hh[u + 1].x, a4);                          \
        a5 = fdot2u(wvs[i1 + 1], hh[u + 1].y, a5);                          \
        a6 = fdot2u(wvs[i1 + 2], hh[u + 1].z, a6);                          \
        a7 = fdot2u(wvs[i1 + 3], hh[u + 1].w, a7);                          \
      }                                                                     \
    }                                                                       \
    float z = ((a0 + a4) + (a1 + a5)) + (((a2 + a6) + (a3 + a7)) + xv);     \
    float e = __expf(2.0f * z);                                             \
    hcur = 1.0f - 2.0f * __builtin_amdgcn_rcpf(e + 1.0f);                   \
    hbuf[(PAR) ^ 1][tid] = (f16)hcur;                                       \
    xv = (float)(NUSE) + bhv;                                               \
    asm volatile("s_waitcnt lgkmcnt(0)" ::: "memory");                      \
    __builtin_amdgcn_s_barrier();                                           \
    __builtin_amdgcn_sched_barrier(0);                                      \
  }

  for (int tt = 0; tt < CT; tt += 4) {
    RNN_STEP(tt + 0, 0, n0, n1)
    RNN_STEP(tt + 1, 1, n1, n2)
    RNN_STEP(tt + 2, 0, n2, n3)
    RNN_STEP(tt + 3, 1, n3, n0)
  }
#undef RNN_STEP

  hstate[b * 256 + tid] = hcur;

  if (t0 + CT == 2048) {                       // fused fp32 classifier head
    hf[tid] = hcur;
    __syncthreads();
    int o = tid >> 4, s2 = tid & 15;
    const float* fw = fc_w + o * 256 + s2 * 16;
    float p = 0.f;
#pragma unroll
    for (int i = 0; i < 16; ++i) p += hf[s2 * 16 + i] * fw[i];
    prt2[o][s2] = p;
    __syncthreads();
    if (tid < 16) {
      float r = fc_b[tid];
#pragma unroll
      for (int s3 = 0; s3 < 16; ++s3) r += prt2[tid][s3];
      out[b * 16 + tid] = r;
    }
  }
}

// ---------------------------------------------------------------------------
extern "C" void kernel_launch(void* const* d_in, const int* in_sizes, int n_in,
                              void* d_out, int out_size, void* d_ws, size_t ws_size,
                              hipStream_t stream) {
  const float* x   = (const float*)d_in[0];
  const float* Wih = (const float*)d_in[1];
  const float* Whh = (const float*)d_in[2];
  const float* bh  = (const float*)d_in[3];
  const float* fcw = (const float*)d_in[4];
  const float* fcb = (const float*)d_in[5];
  float* out = (float*)d_out;

  char* ws = (char*)d_ws;
  uint4* Wfrag  = (uint4*)ws;                        // 128 KB
  uint4* Wc2    = (uint4*)(ws + (128 << 10));        // 128 KB
  float* hstate = (float*)(ws + (256 << 10));        // 256 KB
  f16*   xpb    = (f16*)(ws + (512 << 10));          // chunk buffer

  size_t avail = (ws_size > (size_t)(512 << 10)) ? ws_size - (size_t)(512 << 10) : 0;
  int CT = 2048;
  while (CT > 64 && (size_t)CT * 131072 > avail) CT >>= 1;
  int tpc = CT >> 6;                                 // 64-step tiles per chunk

  prep_kernel<<<64, 256, 0, stream>>>(Wih, Whh, Wfrag, Wc2);
  for (int t0 = 0; t0 < 2048; t0 += CT) {
    gemm_kernel<<<256 * tpc, 256, 0, stream>>>(x, Wfrag, xpb, t0, CT, tpc);
    rnn_kernel<<<256, 256, 0, stream>>>(xpb, Wc2, bh, fcw, fcb, hstate, out, t0, CT);
  }
}